// Round 16
// baseline (198.467 us; speedup 1.0000x reference)
//
#include <hip/hip_runtime.h>
#include <math.h>

#define NR   8192
#define DIM  256
#define QBLK 32

using f32x4  = __attribute__((ext_vector_type(4))) float;
using s4v    = __attribute__((ext_vector_type(4))) short;
using s8v    = __attribute__((ext_vector_type(8))) short;
using bf16x8 = __attribute__((ext_vector_type(8))) short;
typedef _Float16 f16x8 __attribute__((ext_vector_type(8)));
typedef _Float16 f16x4 __attribute__((ext_vector_type(4)));

__device__ __forceinline__ short f2bf(float x){
  union{float f; unsigned u;} v; v.f = x;
  unsigned r = v.u + 0x7fffu + ((v.u >> 16) & 1u);
  return (short)(r >> 16);
}
__device__ __forceinline__ float bf2f(short s){
  union{unsigned u; float f;} v; v.u = ((unsigned)(unsigned short)s) << 16;
  return v.f;
}
__device__ __forceinline__ short f2h(float x){
  union{_Float16 h; short s;} c; c.h = (_Float16)x; return c.s;
}

// ws layout per superstep ss (64 kv rows), 32768 shorts (f16):
//   KH: +0     + p*8192 + (kk*2+n)*512 + l*8 + j   (A-frag: row=l&15, k=(l>>4)*8+j)
//   VT: +16384 + u*512 + l*8 + j, u = par*8+np (PAIRED b128 frags):
//        nf = 2np + (j>>2), jj = j&3:
//        V[ss*64 + par*16 + (l>>4)*4 + jj][nf*16 + (l&15)]
#define SS_SHORTS 32768
#define WS_BYTES_NEEDED (128u * 32768u * 2u)   // 8,388,608

// LDS (shorts): Kh dbuf at {0,16384}; VT tribuf at {32768,49152,65536}
#define LDS8_SHORTS 81920   // 163840 bytes == full 160 KiB pool

__device__ __forceinline__ void dma16(const short* g, short* l){
  __builtin_amdgcn_global_load_lds(
      (const __attribute__((address_space(1))) unsigned int*)g,
      (__attribute__((address_space(3))) unsigned int*)l, 16, 0, 0);
}

__launch_bounds__(256)
__global__ void precompute_ws(const float* __restrict__ Mp, short* __restrict__ ws)
{
  const int tid = threadIdx.x;
  const int bx  = blockIdx.x;        // 128 ss * 16 subblocks
  const int ss  = bx >> 4;
  const int sub = bx & 15;
  const int fi  = sub*256 + tid;     // 0..4095
  const int plane = fi >> 11;        // 0=KH 1=VT
  const int rest  = fi & 2047;
  const int p   = rest >> 10;
  const int cl  = rest & 1023;
  const int ch  = cl >> 6;
  const int l   = cl & 63;
  const int li  = l & 15, g = l >> 4;

  short v[8];
  if (plane == 0){
    const int kk = ch >> 1, n = ch & 1;
    const int row = ss*64 + p*32 + n*16 + li;
    const int d0  = kk*32 + g*8;
    const float* src = Mp + (size_t)row*DIM + d0;
    #pragma unroll
    for (int j = 0; j < 8; ++j) v[j] = f2h(src[j]);
  } else {
    // VT paired: unit u = par*8+np; j<4 -> frag 2np, j>=4 -> frag 2np+1
    const int u   = p*16 + ch;          // 0..31
    const int par = u >> 3;
    const int np  = u & 7;
    #pragma unroll
    for (int j = 0; j < 8; ++j){
      const int nf = 2*np + (j >> 2);
      const int jj = j & 3;
      const int row = ss*64 + par*16 + (l >> 4)*4 + jj;
      const int col = nf*16 + (l & 15);
      v[j] = f2h(Mp[(size_t)row*DIM + col]);
    }
  }
  s8v ov = {v[0],v[1],v[2],v[3],v[4],v[5],v[6],v[7]};
  *(s8v*)(ws + (size_t)ss*SS_SHORTS + plane*16384 + p*8192 + ch*512 + l*8) = ov;
}

__launch_bounds__(512, 2)
__global__ void attn_gate_v11(const float* __restrict__ Np,
                              const float* __restrict__ gw, const float* __restrict__ gwb,
                              const float* __restrict__ gb,
                              const short* __restrict__ ws, float* __restrict__ out)
{
  extern __shared__ short S_[];
  const int tid  = threadIdx.x;
  const int w    = tid >> 6;         // 0..7
  const int lane = tid & 63;
  const int g    = lane >> 4;
  const int li   = lane & 15;
  const int qsub = w & 1;            // which 16 q-rows
  const int par  = w >> 1;           // 0..3: which 16 kv of each 64-tile
  const int qb   = blockIdx.x * QBLK;
  const int fbase = w * 8;           // this wave's 8 DMA fragment-units (of 64)
  const bool isK  = (w < 4);         // waves 0-3 stage KH; 4-7 stage VT

  // ---- Q fragments (f16) from N ----
  f16x8 qh[8];
  {
    const float* qrow = Np + (size_t)(qb + qsub*16 + li) * DIM;
    #pragma unroll
    for (int kk = 0; kk < 8; ++kk){
      const int d0 = kk*32 + g*8;
      #pragma unroll
      for (int j = 0; j < 8; ++j)
        qh[kk][j] = (_Float16)qrow[d0 + j];
    }
  }

  f32x4 o[16];
  #pragma unroll
  for (int nf = 0; nf < 16; ++nf){ f32x4 z = {0.f,0.f,0.f,0.f}; o[nf] = z; }
  float m0 = -1e30f, l0 = 0.0f;      // per q=li (col domain)

  const int p2 = par >> 1, n2 = par & 1;
  const int kfrag_off = p2*8192 + n2*512 + lane*8;   // Kh fragment base (in-buf)

  // buffer rotation state (short offsets into S_)
  int khc = 0;                       // Kh buf holding ss
  int vtr = 65536;                   // VT buf holding ss-1 (garbage at ss=0)
  int vtc = 32768;                   // VT buf holding ss
  int vtf = 49152;                   // VT buf holding ss+1 (filling)

  // ---- prologue: issue DMA for tiles 0 and 1; drain tile 0 only ----
  {
    const int ldst0 = isK ? 0 : (32768 - 16384);
    #pragma unroll
    for (int i = 0; i < 8; ++i){
      const int f = fbase + i;
      dma16(ws + (size_t)f*512 + lane*8, S_ + ldst0 + f*512);
    }
    const int ldst1 = isK ? 16384 : (49152 - 16384);
    #pragma unroll
    for (int i = 0; i < 8; ++i){
      const int f = fbase + i;
      dma16(ws + (size_t)SS_SHORTS + (size_t)f*512 + lane*8, S_ + ldst1 + f*512);
    }
  }
  asm volatile("s_waitcnt vmcnt(8)" ::: "memory");   // tile 0 landed; tile 1 in flight
  __builtin_amdgcn_s_barrier();
  __builtin_amdgcn_sched_barrier(0);

  f16x4 paP;                         // P fragment of previous ss
  paP[0] = (_Float16)0.f; paP[1] = (_Float16)0.f;
  paP[2] = (_Float16)0.f; paP[3] = (_Float16)0.f;

  for (int ss = 0; ss < 128; ++ss){
    // ---- QK^T(ss) (f16): 4 independent 2-MFMA chains ----
    f32x4 sa0, sa1, sa2, sa3;
    { f32x4 z = {0.f,0.f,0.f,0.f}; sa0 = z; sa1 = z; sa2 = z; sa3 = z; }
    {
      const short* kbase = S_ + khc + kfrag_off;
      __builtin_amdgcn_s_setprio(1);
      {
        f16x8 b0 = *(const f16x8*)(kbase);
        f16x8 b1 = *(const f16x8*)(kbase + 1024);
        sa0 = __builtin_amdgcn_mfma_f32_16x16x32_f16(b0, qh[0], sa0, 0, 0, 0);
        sa0 = __builtin_amdgcn_mfma_f32_16x16x32_f16(b1, qh[1], sa0, 0, 0, 0);
      }
      {
        f16x8 b2 = *(const f16x8*)(kbase + 2048);
        f16x8 b3 = *(const f16x8*)(kbase + 3072);
        sa1 = __builtin_amdgcn_mfma_f32_16x16x32_f16(b2, qh[2], sa1, 0, 0, 0);
        sa1 = __builtin_amdgcn_mfma_f32_16x16x32_f16(b3, qh[3], sa1, 0, 0, 0);
      }
      {
        f16x8 b4 = *(const f16x8*)(kbase + 4096);
        f16x8 b5 = *(const f16x8*)(kbase + 5120);
        sa2 = __builtin_amdgcn_mfma_f32_16x16x32_f16(b4, qh[4], sa2, 0, 0, 0);
        sa2 = __builtin_amdgcn_mfma_f32_16x16x32_f16(b5, qh[5], sa2, 0, 0, 0);
      }
      {
        f16x8 b6 = *(const f16x8*)(kbase + 6144);
        f16x8 b7 = *(const f16x8*)(kbase + 7168);
        sa3 = __builtin_amdgcn_mfma_f32_16x16x32_f16(b6, qh[6], sa3, 0, 0, 0);
        sa3 = __builtin_amdgcn_mfma_f32_16x16x32_f16(b7, qh[7], sa3, 0, 0, 0);
      }

      // ---- PV(ss-1): independent of QK^T(ss) -> fills the MFMA pipe ----
      if (ss > 0){
        const short* vbase = S_ + vtr + par*4096 + lane*8;
        #pragma unroll
        for (int np = 0; np < 8; ++np){
          f16x8 v8 = *(const f16x8*)(vbase + np*512);
          f16x4 lo = __builtin_shufflevector(v8, v8, 0, 1, 2, 3);
          f16x4 hi = __builtin_shufflevector(v8, v8, 4, 5, 6, 7);
          o[2*np]   = __builtin_amdgcn_mfma_f32_16x16x16f16(paP, lo, o[2*np],   0, 0, 0);
          o[2*np+1] = __builtin_amdgcn_mfma_f32_16x16x16f16(paP, hi, o[2*np+1], 0, 0, 0);
        }
      }
      __builtin_amdgcn_s_setprio(0);
    }

    // ---- barrier #1: all reads of khc (tile ss) and vtr (tile ss-1) consumed ----
    __builtin_amdgcn_s_barrier();
    __builtin_amdgcn_sched_barrier(0);

    // ---- issue DMA for tile ss+2 into the just-freed buffers ----
    if (ss < 126){
      const size_t nsb = (size_t)(ss + 2) * SS_SHORTS;
      const int ldst = isK ? khc : (vtr - 16384);
      #pragma unroll
      for (int i = 0; i < 8; ++i){
        const int f = fbase + i;
        dma16(ws + nsb + (size_t)f*512 + lane*8, S_ + ldst + f*512);
      }
    }

    // ---- softmax(ss) with defer-max (THR=8) -- covers the DMA flight ----
    const int kvb = ss*64 + par*16 + g*4;     // +i = this lane's kv rows
    const int qg  = qb + qsub*16 + li;        // this lane's q column
    float s_[4];
    #pragma unroll
    for (int i = 0; i < 4; ++i){
      float sv = (sa0[i] + sa1[i]) + (sa2[i] + sa3[i]);
      if (kvb + i == qg) sv = 0.0f;           // zeroed diagonal
      s_[i] = sv;
    }
    const float lmax = fmaxf(fmaxf(s_[0], s_[1]), fmaxf(s_[2], s_[3]));
    float sc = 1.0f;
    if (__any((int)(lmax > m0 + 8.0f))){
      float t = lmax;
      t = fmaxf(t, __shfl_xor(t, 16));
      t = fmaxf(t, __shfl_xor(t, 32));
      const float mn = fmaxf(m0, t);
      sc = __expf(m0 - mn);
      m0 = mn;
      float scr[4];
      #pragma unroll
      for (int i = 0; i < 4; ++i) scr[i] = __shfl(sc, g*4 + i);
      #pragma unroll
      for (int nf = 0; nf < 16; ++nf)
        #pragma unroll
        for (int i = 0; i < 4; ++i) o[nf][i] *= scr[i];
    }

    float p_[4];
    #pragma unroll
    for (int i = 0; i < 4; ++i) p_[i] = __expf(s_[i] - m0);
    paP[0] = (_Float16)p_[0]; paP[1] = (_Float16)p_[1];
    paP[2] = (_Float16)p_[2]; paP[3] = (_Float16)p_[3];

    float ps = (p_[0] + p_[1]) + (p_[2] + p_[3]);
    ps += __shfl_xor(ps, 16);
    ps += __shfl_xor(ps, 32);
    l0 = l0*sc + ps;

    // ---- counted drain: tile ss+1 must be resident; tile ss+2 stays in flight ----
    if (ss < 126){
      asm volatile("s_waitcnt vmcnt(8)" ::: "memory");
    } else {
      asm volatile("s_waitcnt vmcnt(0)" ::: "memory");
    }
    __builtin_amdgcn_s_barrier();
    __builtin_amdgcn_sched_barrier(0);

    // rotate buffers
    const int t = vtr; vtr = vtc; vtc = vtf; vtf = t;
    khc ^= 16384;
  }

  // ---- epilogue PV(127) ----
  {
    const short* vbase = S_ + vtr + par*4096 + lane*8;
    #pragma unroll
    for (int np = 0; np < 8; ++np){
      f16x8 v8 = *(const f16x8*)(vbase + np*512);
      f16x4 lo = __builtin_shufflevector(v8, v8, 0, 1, 2, 3);
      f16x4 hi = __builtin_shufflevector(v8, v8, 4, 5, 6, 7);
      o[2*np]   = __builtin_amdgcn_mfma_f32_16x16x16f16(paP, lo, o[2*np],   0, 0, 0);
      o[2*np+1] = __builtin_amdgcn_mfma_f32_16x16x16f16(paP, hi, o[2*np+1], 0, 0, 0);
    }
  }
  __syncthreads();                   // all VT reads done before dump overwrites LDS

  // ---- transpose m/l from q=li domain to q=4g+i row domain ----
  float mr[4], lr[4];
  #pragma unroll
  for (int i = 0; i < 4; ++i){
    mr[i] = __shfl(m0, g*4 + i);
    lr[i] = __shfl(l0, g*4 + i);
  }

  // ---- merge the four KV partials (flash combine) ----
  float* dump = (float*)S_;
  if (par > 0){
    float* dp = dump + (size_t)((par-1)*128 + qsub*64 + lane) * 72;
    #pragma unroll
    for (int i = 0; i < 4; ++i){ dp[i] = mr[i]; dp[4+i] = lr[i]; }
    #pragma unroll
    for (int nf = 0; nf < 16; ++nf)
      #pragma unroll
      for (int i = 0; i < 4; ++i) dp[8 + nf*4 + i] = o[nf][i];
  }
  __syncthreads();
  if (par == 0){
    #pragma unroll
    for (int pp = 0; pp < 3; ++pp){
      const float* dp = dump + (size_t)(pp*128 + qsub*64 + lane) * 72;
      float a[4], b[4];
      #pragma unroll
      for (int i = 0; i < 4; ++i){
        float mb = dp[i], lb = dp[4+i];
        float mm = fmaxf(mr[i], mb);
        a[i] = __expf(mr[i] - mm);
        b[i] = __expf(mb - mm);
        lr[i] = lr[i]*a[i] + lb*b[i];
        mr[i] = mm;
      }
      #pragma unroll
      for (int nf = 0; nf < 16; ++nf)
        #pragma unroll
        for (int i = 0; i < 4; ++i)
          o[nf][i] = o[nf][i]*a[i] + dp[8 + nf*4 + i]*b[i];
    }

    float inv[4];
    #pragma unroll
    for (int i = 0; i < 4; ++i) inv[i] = 1.0f / lr[i];
    #pragma unroll
    for (int nf = 0; nf < 16; ++nf)
      #pragma unroll
      for (int i = 0; i < 4; ++i) o[nf][i] *= inv[i];

    // ---- gate + blend + store ----
    float acc[4] = {0.f, 0.f, 0.f, 0.f};
    #pragma unroll
    for (int nf = 0; nf < 16; ++nf){
      float wv = gw[nf*16 + li];
      #pragma unroll
      for (int i = 0; i < 4; ++i) acc[i] += o[nf][i] * wv;
    }
    const float bias = gwb[0] + gb[0];
    float gt[4];
    #pragma unroll
    for (int i = 0; i < 4; ++i){
      float x = acc[i];
      x += __shfl_xor(x, 1);
      x += __shfl_xor(x, 2);
      x += __shfl_xor(x, 4);
      x += __shfl_xor(x, 8);
      gt[i] = 1.0f / (1.0f + __expf(-(x + bias)));
    }
    #pragma unroll
    for (int i = 0; i < 4; ++i){
      const int grow = qb + qsub*16 + g*4 + i;
      const float* nrow = Np + (size_t)grow * DIM;
      float* orow = out + (size_t)grow * DIM;
      #pragma unroll
      for (int nf = 0; nf < 16; ++nf){
        const int col = nf*16 + li;
        float nv = nrow[col];
        orow[col] = o[nf][i]*gt[i] + nv*(1.0f - gt[i]);
      }
    }
  }
}

// ============================ V0: fallback (no-ws path, bf16 3-term) ============================
#define KH0 0
#define KH1 8448
#define KL0 16896
#define KL1 25344
#define MT0 33792
#define MT1 44032
#define PBO 54272
#define LDS0_SHORTS 56832

__launch_bounds__(256, 1)
__global__ void attn_gate_v0(const float* __restrict__ Mp, const float* __restrict__ Np,
                             const float* __restrict__ gw, const float* __restrict__ gwb,
                             const float* __restrict__ gb, float* __restrict__ out)
{
  extern __shared__ short S_[];
  const int tid  = threadIdx.x;
  const int w    = tid >> 6;
  const int lane = tid & 63;
  const int g    = lane >> 4;
  const int li   = lane & 15;
  const int qsub = w & 1;
  const int par  = w >> 1;
  const int qb   = blockIdx.x * QBLK;

  short* khp = S_ + (par ? KH1 : KH0);
  short* klp = S_ + (par ? KL1 : KL0);
  short* mtp = S_ + (par ? MT1 : MT0);
  short* pb  = S_ + PBO + w * 640;

  bf16x8 qh[8], ql[8];
  {
    const float* qrow = Np + (size_t)(qb + qsub*16 + li) * DIM;
    #pragma unroll
    for (int kk = 0; kk < 8; ++kk){
      const int d0 = kk*32 + g*8;
      #pragma unroll
      for (int j = 0; j < 8; ++j){
        float f = qrow[d0 + j];
        short h = f2bf(f);
        qh[kk][j] = h;
        ql[kk][j] = f2bf(f - bf2f(h));
      }
    }
  }

  f32x4 o[16];
  #pragma unroll
  for (int nf = 0; nf < 16; ++nf){ f32x4 z = {0.f,0.f,0.f,0.f}; o[nf] = z; }
  float m0[4], l0[4];
  #pragma unroll
  for (int i = 0; i < 4; ++i){ m0[i] = -1e30f; l0[i] = 0.0f; }

  const int NSS = NR / 64;
  for (int ss = 0; ss < NSS; ++ss){
    {
      const int r  = tid >> 2;
      const int cb = (tid & 3) << 6;
      const int p  = r >> 5;
      const int rr = r & 31;
      short* kh = S_ + (p ? KH1 : KH0) + rr*264 + cb;
      short* kl = S_ + (p ? KL1 : KL0) + rr*264 + cb;
      short* mt = S_ + (p ? MT1 : MT0) + rr;
      const float* src = Mp + (size_t)(ss*64 + r) * DIM + cb;
      #pragma unroll
      for (int c = 0; c < 64; c += 4){
        const float4 v = *(const float4*)(src + c);
        float fv[4] = {v.x, v.y, v.z, v.w};
        short h[4], lo[4];
        #pragma unroll
        for (int j = 0; j < 4; ++j){
          h[j]  = f2bf(fv[j]);
          lo[j] = f2bf(fv[j] - bf2f(h[j]));
          mt[(cb + c + j) * 40] = h[j];
        }
        s4v hv = {h[0], h[1], h[2], h[3]};
        s4v lv = {lo[0], lo[1], lo[2], lo[3]};
        *(s4v*)(kh + c) = hv;
        *(s4v*)(kl + c) = lv;
      }
    }
    __syncthreads();

    f32x4 sa[2];
    { f32x4 z = {0.f,0.f,0.f,0.f}; sa[0] = z; sa[1] = z; }
    #pragma unroll
    for (int kk = 0; kk < 8; ++kk){
      #pragma unroll
      for (int n = 0; n < 2; ++n){
        const int a = (n*16 + li)*264 + kk*32 + g*8;
        bf16x8 bh = *(const bf16x8*)(khp + a);
        bf16x8 bl = *(const bf16x8*)(klp + a);
        sa[n] = __builtin_amdgcn_mfma_f32_16x16x32_bf16(qh[kk], bh, sa[n], 0, 0, 0);
        sa[n] = __builtin_amdgcn_mfma_f32_16x16x32_bf16(qh[kk], bl, sa[n], 0, 0, 0);
        sa[n] = __builtin_amdgcn_mfma_f32_16x16x32_bf16(ql[kk], bh, sa[n], 0, 0, 0);
      }
    }

    const int kvb   = ss*64 + par*32;
    const int growb = qb + qsub*16 + g*4;
    float s_[2][4];
    #pragma unroll
    for (int n = 0; n < 2; ++n)
      #pragma unroll
      for (int i = 0; i < 4; ++i){
        float sv = sa[n][i];
        if (kvb + n*16 + li == growb + i) sv = 0.0f;
        s_[n][i] = sv;
      }
    float mn[4], sc[4], ps[4];
    bool need = false;
    #pragma unroll
    for (int i = 0; i < 4; ++i){
      float t = fmaxf(s_[0][i], s_[1][i]);
      t = fmaxf(t, __shfl_xor(t, 1));
      t = fmaxf(t, __shfl_xor(t, 2));
      t = fmaxf(t, __shfl_xor(t, 4));
      t = fmaxf(t, __shfl_xor(t, 8));
      mn[i] = fmaxf(m0[i], t);
      sc[i] = __expf(m0[i] - mn[i]);
      need |= (mn[i] != m0[i]);
      m0[i] = mn[i];
    }
    #pragma unroll
    for (int i = 0; i < 4; ++i) ps[i] = 0.0f;
    #pragma unroll
    for (int n = 0; n < 2; ++n)
      #pragma unroll
      for (int i = 0; i < 4; ++i){
        float p = __expf(s_[n][i] - mn[i]);
        ps[i] += p;
        pb[(g*4 + i)*40 + n*16 + li] = f2bf(p);
      }
    #pragma unroll
    for (int i = 0; i < 4; ++i){
      float t = ps[i];
      t += __shfl_xor(t, 1);
      t += __shfl_xor(t, 2);
      t += __shfl_xor(t, 4);
      t += __shfl_xor(t, 8);
      l0[i] = l0[i]*sc[i] + t;
    }
    if (__any((int)need)){
      #pragma unroll
      for (int nf = 0; nf < 16; ++nf)
        #pragma unroll
        for (int i = 0; i < 4; ++i) o[nf][i] *= sc[i];
    }

    bf16x8 pa = *(const bf16x8*)(pb + li*40 + g*8);
    #pragma unroll
    for (int nf = 0; nf < 16; ++nf){
      bf16x8 bv = *(const bf16x8*)(mtp + (nf*16 + li)*40 + g*8);
      o[nf] = __builtin_amdgcn_mfma_f32_16x16x32_bf16(pa, bv, o[nf], 0, 0, 0);
    }
    __syncthreads();
  }

  float* dump = (float*)S_;
  if (par == 1){
    float* dp = dump + (size_t)(qsub*64 + lane) * 72;
    #pragma unroll
    for (int i = 0; i < 4; ++i){ dp[i] = m0[i]; dp[4+i] = l0[i]; }
    #pragma unroll
    for (int nf = 0; nf < 16; ++nf)
      #pragma unroll
      for (int i = 0; i < 4; ++i) dp[8 + nf*4 + i] = o[nf][i];
  }
  __syncthreads();
  if (par == 0){
    const float* dp = dump + (size_t)(qsub*64 + lane) * 72;
    float a[4], b[4];
    #pragma unroll
    for (int i = 0; i < 4; ++i){
      float mb = dp[i], lb = dp[4+i];
      float mm = fmaxf(m0[i], mb);
      a[i] = __expf(m0[i] - mm);
      b[i] = __expf(mb - mm);
      l0[i] = l0[i]*a[i] + lb*b[i];
    }
    #pragma unroll
    for (int nf = 0; nf < 16; ++nf)
      #pragma unroll
      for (int i = 0; i < 4; ++i)
        o[nf][i] = o[nf][i]*a[i] + dp[8 + nf*4 + i]*b[i];

    float inv[4];
    #pragma unroll
    for (int i = 0; i < 4; ++i) inv[i] = 1.0f / l0[i];
    #pragma unroll
    for (int nf = 0; nf < 16; ++nf)
      #pragma unroll
      for (int i = 0; i < 4; ++i) o[nf][i] *= inv[i];

    float t[4] = {0.f, 0.f, 0.f, 0.f};
    #pragma unroll
    for (int nf = 0; nf < 16; ++nf){
      float wv = gw[nf*16 + li];
      #pragma unroll
      for (int i = 0; i < 4; ++i) t[i] += o[nf][i] * wv;
    }
    const float bias = gwb[0] + gb[0];
    float gt[4];
    #pragma unroll
    for (int i = 0; i < 4; ++i){
      float x = t[i];
      x += __shfl_xor(x, 1);
      x += __shfl_xor(x, 2);
      x += __shfl_xor(x, 4);
      x += __shfl_xor(x, 8);
      gt[i] = 1.0f / (1.0f + __expf(-(x + bias)));
    }
    #pragma unroll
    for (int i = 0; i < 4; ++i){
      const int grow = qb + qsub*16 + g*4 + i;
      const float* nrow = Np + (size_t)grow * DIM;
      float* orow = out + (size_t)grow * DIM;
      #pragma unroll
      for (int nf = 0; nf < 16; ++nf){
        const int col = nf*16 + li;
        float nv = nrow[col];
        orow[col] = o[nf][i]*gt[i] + nv*(1.0f - gt[i]);
      }
    }
  }
}

extern "C" void kernel_launch(void* const* d_in, const int* in_sizes, int n_in,
                              void* d_out, int out_size, void* d_ws, size_t ws_size,
                              hipStream_t stream)
{
  const float* Mp  = (const float*)d_in[0];
  const float* Np  = (const float*)d_in[1];
  const float* gw  = (const float*)d_in[2];
  const float* gwb = (const float*)d_in[3];
  const float* gb  = (const float*)d_in[4];
  float* out = (float*)d_out;

  if (ws_size >= (size_t)WS_BYTES_NEEDED){
    short* ws = (short*)d_ws;
    precompute_ws<<<128*16, 256, 0, stream>>>(Mp, ws);
    const size_t shmem = (size_t)LDS8_SHORTS * sizeof(short);  // 163840 B
    (void)hipFuncSetAttribute((const void*)attn_gate_v11,
                        hipFuncAttributeMaxDynamicSharedMemorySize, (int)shmem);
    attn_gate_v11<<<NR / QBLK, 512, shmem, stream>>>(Np, gw, gwb, gb, ws, out);
  } else {
    const size_t shmem = (size_t)LDS0_SHORTS * sizeof(short);  // 113664 B
    (void)hipFuncSetAttribute((const void*)attn_gate_v0,
                        hipFuncAttributeMaxDynamicSharedMemorySize, (int)shmem);
    attn_gate_v0<<<NR / QBLK, 256, shmem, stream>>>(Mp, Np, gw, gwb, gb, out);
  }
}

// Round 17
// 162.928 us; speedup vs baseline: 1.2181x; 1.2181x over previous
//
#include <hip/hip_runtime.h>
#include <math.h>

#define NR   8192
#define DIM  256
#define QBLK 32

using f32x4  = __attribute__((ext_vector_type(4))) float;
using s4v    = __attribute__((ext_vector_type(4))) short;
using s8v    = __attribute__((ext_vector_type(8))) short;
using bf16x8 = __attribute__((ext_vector_type(8))) short;
typedef _Float16 f16x8 __attribute__((ext_vector_type(8)));
typedef _Float16 f16x4 __attribute__((ext_vector_type(4)));

__device__ __forceinline__ short f2bf(float x){
  union{float f; unsigned u;} v; v.f = x;
  unsigned r = v.u + 0x7fffu + ((v.u >> 16) & 1u);
  return (short)(r >> 16);
}
__device__ __forceinline__ float bf2f(short s){
  union{unsigned u; float f;} v; v.u = ((unsigned)(unsigned short)s) << 16;
  return v.f;
}
__device__ __forceinline__ short f2h(float x){
  union{_Float16 h; short s;} c; c.h = (_Float16)x; return c.s;
}

// ws layout per superstep ss (64 kv rows), 32768 shorts (f16):
//   KH: +0     + p*8192 + (kk*2+n)*512 + l*8 + j   (A-frag: row=l&15, k=(l>>4)*8+j)
//   VT: +16384 + u*512 + l*8 + j, u = par*8+np (PAIRED b128 frags):
//        nf = 2np + (j>>2), jj = j&3:
//        V[ss*64 + par*16 + (l>>4)*4 + jj][nf*16 + (l&15)]
#define SS_SHORTS 32768
#define WS_BYTES_NEEDED (128u * 32768u * 2u)   // 8,388,608

// LDS (shorts): Kh dbuf at {0,16384}; VT tribuf at {32768,49152,65536}
#define LDS8_SHORTS 81920   // 163840 bytes == full 160 KiB pool

__device__ __forceinline__ void dma16(const short* g, short* l){
  __builtin_amdgcn_global_load_lds(
      (const __attribute__((address_space(1))) unsigned int*)g,
      (__attribute__((address_space(3))) unsigned int*)l, 16, 0, 0);
}

__launch_bounds__(256)
__global__ void precompute_ws(const float* __restrict__ Mp, short* __restrict__ ws)
{
  const int tid = threadIdx.x;
  const int bx  = blockIdx.x;        // 128 ss * 16 subblocks
  const int ss  = bx >> 4;
  const int sub = bx & 15;
  const int fi  = sub*256 + tid;     // 0..4095
  const int plane = fi >> 11;        // 0=KH 1=VT
  const int rest  = fi & 2047;
  const int p   = rest >> 10;
  const int cl  = rest & 1023;
  const int ch  = cl >> 6;
  const int l   = cl & 63;
  const int li  = l & 15, g = l >> 4;

  short v[8];
  if (plane == 0){
    const int kk = ch >> 1, n = ch & 1;
    const int row = ss*64 + p*32 + n*16 + li;
    const int d0  = kk*32 + g*8;
    const float* src = Mp + (size_t)row*DIM + d0;
    #pragma unroll
    for (int j = 0; j < 8; ++j) v[j] = f2h(src[j]);
  } else {
    // VT paired: unit u = par*8+np; j<4 -> frag 2np, j>=4 -> frag 2np+1
    const int u   = p*16 + ch;          // 0..31
    const int par = u >> 3;
    const int np  = u & 7;
    #pragma unroll
    for (int j = 0; j < 8; ++j){
      const int nf = 2*np + (j >> 2);
      const int jj = j & 3;
      const int row = ss*64 + par*16 + (l >> 4)*4 + jj;
      const int col = nf*16 + (l & 15);
      v[j] = f2h(Mp[(size_t)row*DIM + col]);
    }
  }
  s8v ov = {v[0],v[1],v[2],v[3],v[4],v[5],v[6],v[7]};
  *(s8v*)(ws + (size_t)ss*SS_SHORTS + plane*16384 + p*8192 + ch*512 + l*8) = ov;
}

__launch_bounds__(512, 2)
__global__ void attn_gate_v12(const float* __restrict__ Np,
                              const float* __restrict__ gw, const float* __restrict__ gwb,
                              const float* __restrict__ gb,
                              const short* __restrict__ ws, float* __restrict__ out)
{
  extern __shared__ short S_[];
  const int tid  = threadIdx.x;
  const int w    = tid >> 6;         // 0..7
  const int lane = tid & 63;
  const int g    = lane >> 4;
  const int li   = lane & 15;
  const int qsub = w & 1;            // which 16 q-rows
  const int par  = w >> 1;           // 0..3: which 16 kv of each 64-tile
  const int qb   = blockIdx.x * QBLK;
  const int fbase = w * 8;           // this wave's 8 DMA fragment-units (of 64)
  const bool isK  = (w < 4);         // waves 0-3 stage KH; 4-7 stage VT

  // ---- Q fragments (f16) from N ----
  f16x8 qh[8];
  {
    const float* qrow = Np + (size_t)(qb + qsub*16 + li) * DIM;
    #pragma unroll
    for (int kk = 0; kk < 8; ++kk){
      const int d0 = kk*32 + g*8;
      #pragma unroll
      for (int j = 0; j < 8; ++j)
        qh[kk][j] = (_Float16)qrow[d0 + j];
    }
  }

  f32x4 o[16];
  #pragma unroll
  for (int nf = 0; nf < 16; ++nf){ f32x4 z = {0.f,0.f,0.f,0.f}; o[nf] = z; }
  float m0 = -1e30f, l0 = 0.0f;      // m shared per column group; l per-lane partial

  const int p2 = par >> 1, n2 = par & 1;
  const int kfrag_off = p2*8192 + n2*512 + lane*8;   // Kh fragment base (in-buf)

  // buffer rotation state (short offsets into S_)
  int khc = 0;                       // Kh buf holding ss
  int vtr = 65536;                   // VT buf holding ss-1 (garbage at ss=0)
  int vtc = 32768;                   // VT buf holding ss
  int vtf = 49152;                   // VT fill target for ss+1

  // ---- prologue: DMA ss=0 (KH->khc, VT->vtc) ----
  {
    const int ldst = isK ? 0 : (32768 - 16384);
    #pragma unroll
    for (int i = 0; i < 8; ++i){
      const int f = fbase + i;
      dma16(ws + (size_t)f*512 + lane*8, S_ + ldst + f*512);
    }
  }
  __syncthreads();

  f16x4 paP;                         // P fragment of previous ss
  paP[0] = (_Float16)0.f; paP[1] = (_Float16)0.f;
  paP[2] = (_Float16)0.f; paP[3] = (_Float16)0.f;

  for (int ss = 0; ss < 128; ++ss){
    const size_t ssb = (size_t)ss * SS_SHORTS;

    // issue DMA for ss+1 (KH -> khc^16384, VT -> vtf)
    if (ss < 127){
      const size_t nsb = ssb + SS_SHORTS;
      const int ldst = isK ? (khc ^ 16384) : (vtf - 16384);
      #pragma unroll
      for (int i = 0; i < 8; ++i){
        const int f = fbase + i;
        dma16(ws + nsb + (size_t)f*512 + lane*8, S_ + ldst + f*512);
      }
    }

    // ---- QK^T(ss) (f16): 4 independent 2-MFMA chains ----
    f32x4 sa0, sa1, sa2, sa3;
    { f32x4 z = {0.f,0.f,0.f,0.f}; sa0 = z; sa1 = z; sa2 = z; sa3 = z; }
    {
      const short* kbase = S_ + khc + kfrag_off;
      __builtin_amdgcn_s_setprio(1);
      {
        f16x8 b0 = *(const f16x8*)(kbase);
        f16x8 b1 = *(const f16x8*)(kbase + 1024);
        sa0 = __builtin_amdgcn_mfma_f32_16x16x32_f16(b0, qh[0], sa0, 0, 0, 0);
        sa0 = __builtin_amdgcn_mfma_f32_16x16x32_f16(b1, qh[1], sa0, 0, 0, 0);
      }
      {
        f16x8 b2 = *(const f16x8*)(kbase + 2048);
        f16x8 b3 = *(const f16x8*)(kbase + 3072);
        sa1 = __builtin_amdgcn_mfma_f32_16x16x32_f16(b2, qh[2], sa1, 0, 0, 0);
        sa1 = __builtin_amdgcn_mfma_f32_16x16x32_f16(b3, qh[3], sa1, 0, 0, 0);
      }
      {
        f16x8 b4 = *(const f16x8*)(kbase + 4096);
        f16x8 b5 = *(const f16x8*)(kbase + 5120);
        sa2 = __builtin_amdgcn_mfma_f32_16x16x32_f16(b4, qh[4], sa2, 0, 0, 0);
        sa2 = __builtin_amdgcn_mfma_f32_16x16x32_f16(b5, qh[5], sa2, 0, 0, 0);
      }
      {
        f16x8 b6 = *(const f16x8*)(kbase + 6144);
        f16x8 b7 = *(const f16x8*)(kbase + 7168);
        sa3 = __builtin_amdgcn_mfma_f32_16x16x32_f16(b6, qh[6], sa3, 0, 0, 0);
        sa3 = __builtin_amdgcn_mfma_f32_16x16x32_f16(b7, qh[7], sa3, 0, 0, 0);
      }

      // ---- PV(ss-1): independent of QK^T(ss) -> fills the MFMA pipe ----
      if (ss > 0){
        const short* vbase = S_ + vtr + par*4096 + lane*8;
        #pragma unroll
        for (int np = 0; np < 8; ++np){
          f16x8 v8 = *(const f16x8*)(vbase + np*512);
          f16x4 lo = __builtin_shufflevector(v8, v8, 0, 1, 2, 3);
          f16x4 hi = __builtin_shufflevector(v8, v8, 4, 5, 6, 7);
          o[2*np]   = __builtin_amdgcn_mfma_f32_16x16x16f16(paP, lo, o[2*np],   0, 0, 0);
          o[2*np+1] = __builtin_amdgcn_mfma_f32_16x16x16f16(paP, hi, o[2*np+1], 0, 0, 0);
        }
      }
      __builtin_amdgcn_s_setprio(0);
    }

    // ---- softmax(ss) with defer-max (THR=8); l kept as per-lane partial ----
    const int kvb = ss*64 + par*16 + g*4;     // +i = this lane's kv rows
    const int qg  = qb + qsub*16 + li;        // this lane's q column
    float s_[4];
    #pragma unroll
    for (int i = 0; i < 4; ++i){
      float sv = (sa0[i] + sa1[i]) + (sa2[i] + sa3[i]);
      if (kvb + i == qg) sv = 0.0f;           // zeroed diagonal
      s_[i] = sv;
    }
    const float lmax = fmaxf(fmaxf(s_[0], s_[1]), fmaxf(s_[2], s_[3]));
    float sc = 1.0f;
    if (__any((int)(lmax > m0 + 8.0f))){
      float t = lmax;
      t = fmaxf(t, __shfl_xor(t, 16));
      t = fmaxf(t, __shfl_xor(t, 32));
      const float mn = fmaxf(m0, t);
      sc = __expf(m0 - mn);
      m0 = mn;
      float scr[4];
      #pragma unroll
      for (int i = 0; i < 4; ++i) scr[i] = __shfl(sc, g*4 + i);
      #pragma unroll
      for (int nf = 0; nf < 16; ++nf)
        #pragma unroll
        for (int i = 0; i < 4; ++i) o[nf][i] *= scr[i];
    }

    float p_[4];
    #pragma unroll
    for (int i = 0; i < 4; ++i) p_[i] = __expf(s_[i] - m0);
    paP[0] = (_Float16)p_[0]; paP[1] = (_Float16)p_[1];
    paP[2] = (_Float16)p_[2]; paP[3] = (_Float16)p_[3];

    // deferred l-sum: per-lane partial only (cross-lane reduce after the loop)
    l0 = l0*sc + ((p_[0] + p_[1]) + (p_[2] + p_[3]));

    __syncthreads();                 // drains DMA(ss+1); protects buffers

    // rotate buffers
    const int t = vtr; vtr = vtc; vtc = vtf; vtf = t;
    khc ^= 16384;
  }

  // ---- epilogue PV(127) ----
  {
    const short* vbase = S_ + vtr + par*4096 + lane*8;
    #pragma unroll
    for (int np = 0; np < 8; ++np){
      f16x8 v8 = *(const f16x8*)(vbase + np*512);
      f16x4 lo = __builtin_shufflevector(v8, v8, 0, 1, 2, 3);
      f16x4 hi = __builtin_shufflevector(v8, v8, 4, 5, 6, 7);
      o[2*np]   = __builtin_amdgcn_mfma_f32_16x16x16f16(paP, lo, o[2*np],   0, 0, 0);
      o[2*np+1] = __builtin_amdgcn_mfma_f32_16x16x16f16(paP, hi, o[2*np+1], 0, 0, 0);
    }
  }
  // finish the deferred l reduction (column group = lanes li, li+16, li+32, li+48)
  l0 += __shfl_xor(l0, 16);
  l0 += __shfl_xor(l0, 32);
  __syncthreads();                   // all VT reads done before dump overwrites LDS

  // ---- transpose m/l from q=li domain to q=4g+i row domain ----
  float mr[4], lr[4];
  #pragma unroll
  for (int i = 0; i < 4; ++i){
    mr[i] = __shfl(m0, g*4 + i);
    lr[i] = __shfl(l0, g*4 + i);
  }

  // ---- merge the four KV partials (flash combine) ----
  float* dump = (float*)S_;
  if (par > 0){
    float* dp = dump + (size_t)((par-1)*128 + qsub*64 + lane) * 72;
    #pragma unroll
    for (int i = 0; i < 4; ++i){ dp[i] = mr[i]; dp[4+i] = lr[i]; }
    #pragma unroll
    for (int nf = 0; nf < 16; ++nf)
      #pragma unroll
      for (int i = 0; i < 4; ++i) dp[8 + nf*4 + i] = o[nf][i];
  }
  __syncthreads();
  if (par == 0){
    #pragma unroll
    for (int pp = 0; pp < 3; ++pp){
      const float* dp = dump + (size_t)(pp*128 + qsub*64 + lane) * 72;
      float a[4], b[4];
      #pragma unroll
      for (int i = 0; i < 4; ++i){
        float mb = dp[i], lb = dp[4+i];
        float mm = fmaxf(mr[i], mb);
        a[i] = __expf(mr[i] - mm);
        b[i] = __expf(mb - mm);
        lr[i] = lr[i]*a[i] + lb*b[i];
        mr[i] = mm;
      }
      #pragma unroll
      for (int nf = 0; nf < 16; ++nf)
        #pragma unroll
        for (int i = 0; i < 4; ++i)
          o[nf][i] = o[nf][i]*a[i] + dp[8 + nf*4 + i]*b[i];
    }

    float inv[4];
    #pragma unroll
    for (int i = 0; i < 4; ++i) inv[i] = 1.0f / lr[i];
    #pragma unroll
    for (int nf = 0; nf < 16; ++nf)
      #pragma unroll
      for (int i = 0; i < 4; ++i) o[nf][i] *= inv[i];

    // ---- gate + blend + store ----
    float acc[4] = {0.f, 0.f, 0.f, 0.f};
    #pragma unroll
    for (int nf = 0; nf < 16; ++nf){
      float wv = gw[nf*16 + li];
      #pragma unroll
      for (int i = 0; i < 4; ++i) acc[i] += o[nf][i] * wv;
    }
    const float bias = gwb[0] + gb[0];
    float gt[4];
    #pragma unroll
    for (int i = 0; i < 4; ++i){
      float x = acc[i];
      x += __shfl_xor(x, 1);
      x += __shfl_xor(x, 2);
      x += __shfl_xor(x, 4);
      x += __shfl_xor(x, 8);
      gt[i] = 1.0f / (1.0f + __expf(-(x + bias)));
    }
    #pragma unroll
    for (int i = 0; i < 4; ++i){
      const int grow = qb + qsub*16 + g*4 + i;
      const float* nrow = Np + (size_t)grow * DIM;
      float* orow = out + (size_t)grow * DIM;
      #pragma unroll
      for (int nf = 0; nf < 16; ++nf){
        const int col = nf*16 + li;
        float nv = nrow[col];
        orow[col] = o[nf][i]*gt[i] + nv*(1.0f - gt[i]);
      }
    }
  }
}

// ============================ V0: fallback (no-ws path, bf16 3-term) ============================
#define KH0 0
#define KH1 8448
#define KL0 16896
#define KL1 25344
#define MT0 33792
#define MT1 44032
#define PBO 54272
#define LDS0_SHORTS 56832

__launch_bounds__(256, 1)
__global__ void attn_gate_v0(const float* __restrict__ Mp, const float* __restrict__ Np,
                             const float* __restrict__ gw, const float* __restrict__ gwb,
                             const float* __restrict__ gb, float* __restrict__ out)
{
  extern __shared__ short S_[];
  const int tid  = threadIdx.x;
  const int w    = tid >> 6;
  const int lane = tid & 63;
  const int g    = lane >> 4;
  const int li   = lane & 15;
  const int qsub = w & 1;
  const int par  = w >> 1;
  const int qb   = blockIdx.x * QBLK;

  short* khp = S_ + (par ? KH1 : KH0);
  short* klp = S_ + (par ? KL1 : KL0);
  short* mtp = S_ + (par ? MT1 : MT0);
  short* pb  = S_ + PBO + w * 640;

  bf16x8 qh[8], ql[8];
  {
    const float* qrow = Np + (size_t)(qb + qsub*16 + li) * DIM;
    #pragma unroll
    for (int kk = 0; kk < 8; ++kk){
      const int d0 = kk*32 + g*8;
      #pragma unroll
      for (int j = 0; j < 8; ++j){
        float f = qrow[d0 + j];
        short h = f2bf(f);
        qh[kk][j] = h;
        ql[kk][j] = f2bf(f - bf2f(h));
      }
    }
  }

  f32x4 o[16];
  #pragma unroll
  for (int nf = 0; nf < 16; ++nf){ f32x4 z = {0.f,0.f,0.f,0.f}; o[nf] = z; }
  float m0[4], l0[4];
  #pragma unroll
  for (int i = 0; i < 4; ++i){ m0[i] = -1e30f; l0[i] = 0.0f; }

  const int NSS = NR / 64;
  for (int ss = 0; ss < NSS; ++ss){
    {
      const int r  = tid >> 2;
      const int cb = (tid & 3) << 6;
      const int p  = r >> 5;
      const int rr = r & 31;
      short* kh = S_ + (p ? KH1 : KH0) + rr*264 + cb;
      short* kl = S_ + (p ? KL1 : KL0) + rr*264 + cb;
      short* mt = S_ + (p ? MT1 : MT0) + rr;
      const float* src = Mp + (size_t)(ss*64 + r) * DIM + cb;
      #pragma unroll
      for (int c = 0; c < 64; c += 4){
        const float4 v = *(const float4*)(src + c);
        float fv[4] = {v.x, v.y, v.z, v.w};
        short h[4], lo[4];
        #pragma unroll
        for (int j = 0; j < 4; ++j){
          h[j]  = f2bf(fv[j]);
          lo[j] = f2bf(fv[j] - bf2f(h[j]));
          mt[(cb + c + j) * 40] = h[j];
        }
        s4v hv = {h[0], h[1], h[2], h[3]};
        s4v lv = {lo[0], lo[1], lo[2], lo[3]};
        *(s4v*)(kh + c) = hv;
        *(s4v*)(kl + c) = lv;
      }
    }
    __syncthreads();

    f32x4 sa[2];
    { f32x4 z = {0.f,0.f,0.f,0.f}; sa[0] = z; sa[1] = z; }
    #pragma unroll
    for (int kk = 0; kk < 8; ++kk){
      #pragma unroll
      for (int n = 0; n < 2; ++n){
        const int a = (n*16 + li)*264 + kk*32 + g*8;
        bf16x8 bh = *(const bf16x8*)(khp + a);
        bf16x8 bl = *(const bf16x8*)(klp + a);
        sa[n] = __builtin_amdgcn_mfma_f32_16x16x32_bf16(qh[kk], bh, sa[n], 0, 0, 0);
        sa[n] = __builtin_amdgcn_mfma_f32_16x16x32_bf16(qh[kk], bl, sa[n], 0, 0, 0);
        sa[n] = __builtin_amdgcn_mfma_f32_16x16x32_bf16(ql[kk], bh, sa[n], 0, 0, 0);
      }
    }

    const int kvb   = ss*64 + par*32;
    const int growb = qb + qsub*16 + g*4;
    float s_[2][4];
    #pragma unroll
    for (int n = 0; n < 2; ++n)
      #pragma unroll
      for (int i = 0; i < 4; ++i){
        float sv = sa[n][i];
        if (kvb + n*16 + li == growb + i) sv = 0.0f;
        s_[n][i] = sv;
      }
    float mn[4], sc[4], ps[4];
    bool need = false;
    #pragma unroll
    for (int i = 0; i < 4; ++i){
      float t = fmaxf(s_[0][i], s_[1][i]);
      t = fmaxf(t, __shfl_xor(t, 1));
      t = fmaxf(t, __shfl_xor(t, 2));
      t = fmaxf(t, __shfl_xor(t, 4));
      t = fmaxf(t, __shfl_xor(t, 8));
      mn[i] = fmaxf(m0[i], t);
      sc[i] = __expf(m0[i] - mn[i]);
      need |= (mn[i] != m0[i]);
      m0[i] = mn[i];
    }
    #pragma unroll
    for (int i = 0; i < 4; ++i) ps[i] = 0.0f;
    #pragma unroll
    for (int n = 0; n < 2; ++n)
      #pragma unroll
      for (int i = 0; i < 4; ++i){
        float p = __expf(s_[n][i] - mn[i]);
        ps[i] += p;
        pb[(g*4 + i)*40 + n*16 + li] = f2bf(p);
      }
    #pragma unroll
    for (int i = 0; i < 4; ++i){
      float t = ps[i];
      t += __shfl_xor(t, 1);
      t += __shfl_xor(t, 2);
      t += __shfl_xor(t, 4);
      t += __shfl_xor(t, 8);
      l0[i] = l0[i]*sc[i] + t;
    }
    if (__any((int)need)){
      #pragma unroll
      for (int nf = 0; nf < 16; ++nf)
        #pragma unroll
        for (int i = 0; i < 4; ++i) o[nf][i] *= sc[i];
    }

    bf16x8 pa = *(const bf16x8*)(pb + li*40 + g*8);
    #pragma unroll
    for (int nf = 0; nf < 16; ++nf){
      bf16x8 bv = *(const bf16x8*)(mtp + (nf*16 + li)*40 + g*8);
      o[nf] = __builtin_amdgcn_mfma_f32_16x16x32_bf16(pa, bv, o[nf], 0, 0, 0);
    }
    __syncthreads();
  }

  float* dump = (float*)S_;
  if (par == 1){
    float* dp = dump + (size_t)(qsub*64 + lane) * 72;
    #pragma unroll
    for (int i = 0; i < 4; ++i){ dp[i] = m0[i]; dp[4+i] = l0[i]; }
    #pragma unroll
    for (int nf = 0; nf < 16; ++nf)
      #pragma unroll
      for (int i = 0; i < 4; ++i) dp[8 + nf*4 + i] = o[nf][i];
  }
  __syncthreads();
  if (par == 0){
    const float* dp = dump + (size_t)(qsub*64 + lane) * 72;
    float a[4], b[4];
    #pragma unroll
    for (int i = 0; i < 4; ++i){
      float mb = dp[i], lb = dp[4+i];
      float mm = fmaxf(m0[i], mb);
      a[i] = __expf(m0[i] - mm);
      b[i] = __expf(mb - mm);
      l0[i] = l0[i]*a[i] + lb*b[i];
    }
    #pragma unroll
    for (int nf = 0; nf < 16; ++nf)
      #pragma unroll
      for (int i = 0; i < 4; ++i)
        o[nf][i] = o[nf][i]*a[i] + dp[8 + nf*4 + i]*b[i];

    float inv[4];
    #pragma unroll
    for (int i = 0; i < 4; ++i) inv[i] = 1.0f / l0[i];
    #pragma unroll
    for (int nf = 0; nf < 16; ++nf)
      #pragma unroll
      for (int i = 0; i < 4; ++i) o[nf][i] *= inv[i];

    float t[4] = {0.f, 0.f, 0.f, 0.f};
    #pragma unroll
    for (int nf = 0; nf < 16; ++nf){
      float wv = gw[nf*16 + li];
      #pragma unroll
      for (int i = 0; i < 4; ++i) t[i] += o[nf][i] * wv;
    }
    const float bias = gwb[0] + gb[0];
    float gt[4];
    #pragma unroll
    for (int i = 0; i < 4; ++i){
      float x = t[i];
      x += __shfl_xor(x, 1);
      x += __shfl_xor(x, 2);
      x += __shfl_xor(x, 4);
      x += __shfl_xor(x, 8);
      gt[i] = 1.0f / (1.0f + __expf(-(x + bias)));
    }
    #pragma unroll
    for (int i = 0; i < 4; ++i){
      const int grow = qb + qsub*16 + g*4 + i;
      const float* nrow = Np + (size_t)grow * DIM;
      float* orow = out + (size_t)grow * DIM;
      #pragma unroll
      for (int nf = 0; nf < 16; ++nf){
        const int col = nf*16 + li;
        float nv = nrow[col];
        orow[col] = o[nf][i]*gt[i] + nv*(1.0f - gt[i]);
      }
    }
  }
}

extern "C" void kernel_launch(void* const* d_in, const int* in_sizes, int n_in,
                              void* d_out, int out_size, void* d_ws, size_t ws_size,
                              hipStream_t stream)
{
  const float* Mp  = (const float*)d_in[0];
  const float* Np  = (const float*)d_in[1];
  const float* gw  = (const float*)d_in[2];
  const float* gwb = (const float*)d_in[3];
  const float* gb  = (const float*)d_in[4];
  float* out = (float*)d_out;

  if (ws_size >= (size_t)WS_BYTES_NEEDED){
    short* ws = (short*)d_ws;
    precompute_ws<<<128*16, 256, 0, stream>>>(Mp, ws);
    const size_t shmem = (size_t)LDS8_SHORTS * sizeof(short);  // 163840 B
    (void)hipFuncSetAttribute((const void*)attn_gate_v12,
                        hipFuncAttributeMaxDynamicSharedMemorySize, (int)shmem);
    attn_gate_v12<<<NR / QBLK, 512, shmem, stream>>>(Np, gw, gwb, gb, ws, out);
  } else {
    const size_t shmem = (size_t)LDS0_SHORTS * sizeof(short);  // 113664 B
    (void)hipFuncSetAttribute((const void*)attn_gate_v0,
                        hipFuncAttributeMaxDynamicSharedMemorySize, (int)shmem);
    attn_gate_v0<<<NR / QBLK, 256, shmem, stream>>>(Mp, Np, gw, gwb, gb, out);
  }
}